// Round 6
// baseline (7302.734 us; speedup 1.0000x reference)
//
#include <hip/hip_runtime.h>
#include <math.h>

#define DMODEL 1024
#define NHEADS 16
#define DKV    64
#define FFDIM  4096
#define SEQ    2048
#define BATCH  4
#define NTOK   (BATCH * SEQ)
#define LN_EPS 1e-5f

// Workspace budget: 3 slots x (NTOK*DMODEL) floats = 3 x 32 MB = 96 MB.
//   slot0: Q  -> CTX (attn in-place) -> F2
//   slot1: K  -> ATT (O-proj out)    -> H (LN1 in-place)
//   slot2: V  -> F1 row-chunks (2048 x 4096 = 32 MB each)

// ---------------------------------------------------------------------------
// GEMM: C[M,N] = A[M,K] @ B[K,N] + bias[N], optional ReLU.
// 128x128 tile, BK=8, 256 threads, 8x8 outputs/thread, fp32 vector FMA.
// B-fragment column split (tx*4 and 64+tx*4): lane addr stride 16B -> free
// 2-way LDS bank aliasing instead of 4-way conflict at stride 32B.
// ---------------------------------------------------------------------------
template <bool RELU>
__global__ __launch_bounds__(256) void gemm_bias_kernel(
    const float* __restrict__ A, const float* __restrict__ B,
    const float* __restrict__ bias, float* __restrict__ C,
    int M, int N, int K)
{
    __shared__ float As[8][128];   // transposed A tile: As[k][m]
    __shared__ float Bs[8][128];   // Bs[k][n]

    const int tid  = threadIdx.x;
    const int brow = blockIdx.y * 128;
    const int bcol = blockIdx.x * 128;
    const int ty   = tid >> 4;          // 0..15 -> output row group (8 rows)
    const int tx   = tid & 15;          // 0..15 -> output col group (4+4 cols)

    const int arow = tid >> 1;          // 0..127
    const int acol = (tid & 1) * 4;     // 0 or 4
    const int brw  = tid >> 5;          // 0..7
    const int bcl  = (tid & 31) * 4;    // 0..124

    float acc[8][8];
#pragma unroll
    for (int i = 0; i < 8; ++i)
#pragma unroll
        for (int j = 0; j < 8; ++j) acc[i][j] = 0.f;

    const float* Ap = A + (size_t)(brow + arow) * K + acol;
    const float* Bp = B + (size_t)brw * N + bcol + bcl;

    for (int k0 = 0; k0 < K; k0 += 8) {
        float4 a4 = *(const float4*)(Ap + k0);
        float4 b4 = *(const float4*)(Bp + (size_t)k0 * N);
        As[acol + 0][arow] = a4.x;
        As[acol + 1][arow] = a4.y;
        As[acol + 2][arow] = a4.z;
        As[acol + 3][arow] = a4.w;
        *(float4*)&Bs[brw][bcl] = b4;
        __syncthreads();
#pragma unroll
        for (int k = 0; k < 8; ++k) {
            float4 a0 = *(const float4*)&As[k][ty * 8];
            float4 a1 = *(const float4*)&As[k][ty * 8 + 4];
            float4 b0 = *(const float4*)&Bs[k][tx * 4];        // half-tile 0
            float4 b1 = *(const float4*)&Bs[k][64 + tx * 4];   // half-tile 1
            float ar[8] = {a0.x, a0.y, a0.z, a0.w, a1.x, a1.y, a1.z, a1.w};
            float br[8] = {b0.x, b0.y, b0.z, b0.w, b1.x, b1.y, b1.z, b1.w};
#pragma unroll
            for (int i = 0; i < 8; ++i)
#pragma unroll
                for (int j = 0; j < 8; ++j)
                    acc[i][j] = fmaf(ar[i], br[j], acc[i][j]);
        }
        __syncthreads();
    }

    float4 bb0 = *(const float4*)&bias[bcol + tx * 4];
    float4 bb1 = *(const float4*)&bias[bcol + 64 + tx * 4];
    float bv[8] = {bb0.x, bb0.y, bb0.z, bb0.w, bb1.x, bb1.y, bb1.z, bb1.w};
#pragma unroll
    for (int i = 0; i < 8; ++i) {
        size_t row = (size_t)(brow + ty * 8 + i);
        float o[8];
#pragma unroll
        for (int j = 0; j < 8; ++j) {
            o[j] = acc[i][j] + bv[j];
            if (RELU) o[j] = fmaxf(o[j], 0.f);
        }
        *(float4*)&C[row * N + bcol + tx * 4]      = make_float4(o[0], o[1], o[2], o[3]);
        *(float4*)&C[row * N + bcol + 64 + tx * 4] = make_float4(o[4], o[5], o[6], o[7]);
    }
}

// ---------------------------------------------------------------------------
// Flash-style attention, fp32. grid = (SEQ/64, NHEADS, BATCH), 64 threads.
// CTX may alias Q (in-place): each lane reads exactly the Q elements it
// later overwrites (same addresses, program-order dependency), and K/V are
// separate buffers. No __restrict__ on Q/CTX because they alias.
// ---------------------------------------------------------------------------
__global__ __launch_bounds__(64, 1) void attn_kernel(
    const float* Q, const float* __restrict__ K,
    const float* __restrict__ V, float* CTX)
{
    __shared__ float Kt[64][64];
    __shared__ float Vt[64][64];

    const int qt   = blockIdx.x;   // 0..31
    const int h    = blockIdx.y;   // 0..15
    const int b    = blockIdx.z;   // 0..3
    const int lane = threadIdx.x;  // 0..63

    const size_t headbase = (size_t)(b * SEQ) * DMODEL + (size_t)h * DKV;
    const float* qrow = Q + headbase + (size_t)(qt * 64 + lane) * DMODEL;

    float q[64];
#pragma unroll
    for (int d = 0; d < 64; d += 4) {
        float4 t = *(const float4*)&qrow[d];
        q[d]     = t.x * 0.125f;   // fold 1/sqrt(dk)=1/8 into q
        q[d + 1] = t.y * 0.125f;
        q[d + 2] = t.z * 0.125f;
        q[d + 3] = t.w * 0.125f;
    }
    float acc[64];
#pragma unroll
    for (int d = 0; d < 64; ++d) acc[d] = 0.f;
    float m = -INFINITY, l = 0.f;

    const int r4 = lane >> 4;         // 0..3
    const int c4 = (lane & 15) * 4;   // 0..60

    for (int kt = 0; kt < SEQ / 64; ++kt) {
        const float* Kg = K + headbase + (size_t)(kt * 64) * DMODEL;
        const float* Vg = V + headbase + (size_t)(kt * 64) * DMODEL;
#pragma unroll
        for (int rr = 0; rr < 64; rr += 4) {
            int r = rr + r4;
            *(float4*)&Kt[r][c4] = *(const float4*)&Kg[(size_t)r * DMODEL + c4];
            *(float4*)&Vt[r][c4] = *(const float4*)&Vg[(size_t)r * DMODEL + c4];
        }
        __syncthreads();
#pragma unroll 1
        for (int kk = 0; kk < 64; ++kk) {
            float s0 = 0.f, s1 = 0.f, s2 = 0.f, s3 = 0.f;
#pragma unroll
            for (int d = 0; d < 64; d += 4) {
                float4 kv = *(const float4*)&Kt[kk][d];
                s0 = fmaf(q[d],     kv.x, s0);
                s1 = fmaf(q[d + 1], kv.y, s1);
                s2 = fmaf(q[d + 2], kv.z, s2);
                s3 = fmaf(q[d + 3], kv.w, s3);
            }
            float s = (s0 + s1) + (s2 + s3);
            if (s > m) {                 // rare after warm-up
                float c = __expf(m - s);
                l *= c;
#pragma unroll
                for (int d = 0; d < 64; ++d) acc[d] *= c;
                m = s;
            }
            float p = __expf(s - m);
            l += p;
#pragma unroll
            for (int d = 0; d < 64; d += 4) {
                float4 vv = *(const float4*)&Vt[kk][d];
                acc[d]     = fmaf(p, vv.x, acc[d]);
                acc[d + 1] = fmaf(p, vv.y, acc[d + 1]);
                acc[d + 2] = fmaf(p, vv.z, acc[d + 2]);
                acc[d + 3] = fmaf(p, vv.w, acc[d + 3]);
            }
        }
        __syncthreads();
    }

    const float invl = 1.0f / l;
    float* orow = CTX + headbase + (size_t)(qt * 64 + lane) * DMODEL;
#pragma unroll
    for (int d = 0; d < 64; d += 4) {
        *(float4*)&orow[d] = make_float4(acc[d] * invl, acc[d + 1] * invl,
                                         acc[d + 2] * invl, acc[d + 3] * invl);
    }
}

// ---------------------------------------------------------------------------
// OUT[row] = LayerNorm(X[row] + Y[row]) * g + be.  One block per row.
// OUT may alias Y (in-place LN over the residual input): per-thread loads
// precede the store at the same address. No __restrict__ on X/Y/OUT.
// ---------------------------------------------------------------------------
__global__ __launch_bounds__(256) void add_ln_kernel(
    const float* X, const float* Y,
    const float* __restrict__ g, const float* __restrict__ be,
    float* OUT)
{
    const int row = blockIdx.x;
    const int tid = threadIdx.x;
    const size_t base = (size_t)row * DMODEL + (size_t)tid * 4;

    float4 x4 = *(const float4*)&X[base];
    float4 y4 = *(const float4*)&Y[base];
    float4 s4 = make_float4(x4.x + y4.x, x4.y + y4.y, x4.z + y4.z, x4.w + y4.w);
    float sum = s4.x + s4.y + s4.z + s4.w;
    float sq  = s4.x * s4.x + s4.y * s4.y + s4.z * s4.z + s4.w * s4.w;
#pragma unroll
    for (int off = 32; off > 0; off >>= 1) {
        sum += __shfl_down(sum, off);
        sq  += __shfl_down(sq, off);
    }
    __shared__ float red[8];
    const int wid = tid >> 6, ln = tid & 63;
    if (ln == 0) { red[wid] = sum; red[4 + wid] = sq; }
    __syncthreads();
    if (tid == 0) {
        float s  = red[0] + red[1] + red[2] + red[3];
        float qq = red[4] + red[5] + red[6] + red[7];
        float mu  = s * (1.0f / DMODEL);
        float var = qq * (1.0f / DMODEL) - mu * mu;
        red[0] = mu;
        red[1] = rsqrtf(var + LN_EPS);
    }
    __syncthreads();
    const float mu = red[0], rs = red[1];
    float4 g4 = *(const float4*)&g[(size_t)tid * 4];
    float4 b4 = *(const float4*)&be[(size_t)tid * 4];
    float4 o;
    o.x = (s4.x - mu) * rs * g4.x + b4.x;
    o.y = (s4.y - mu) * rs * g4.y + b4.y;
    o.z = (s4.z - mu) * rs * g4.z + b4.z;
    o.w = (s4.w - mu) * rs * g4.w + b4.w;
    *(float4*)&OUT[base] = o;
}

// ---------------------------------------------------------------------------
extern "C" void kernel_launch(void* const* d_in, const int* in_sizes, int n_in,
                              void* d_out, int out_size, void* d_ws, size_t ws_size,
                              hipStream_t stream)
{
    const float* x   = (const float*)d_in[0];
    const float* Wq  = (const float*)d_in[1];
    const float* bq  = (const float*)d_in[2];
    const float* Wk  = (const float*)d_in[3];
    const float* bk  = (const float*)d_in[4];
    const float* Wv  = (const float*)d_in[5];
    const float* bv  = (const float*)d_in[6];
    const float* Wo  = (const float*)d_in[7];
    const float* bo  = (const float*)d_in[8];
    const float* W1  = (const float*)d_in[9];
    const float* b1  = (const float*)d_in[10];
    const float* W2  = (const float*)d_in[11];
    const float* b2  = (const float*)d_in[12];
    const float* g1  = (const float*)d_in[13];
    const float* be1 = (const float*)d_in[14];
    const float* g2  = (const float*)d_in[15];
    const float* be2 = (const float*)d_in[16];
    float* out = (float*)d_out;

    float* ws = (float*)d_ws;
    const size_t T = (size_t)NTOK * DMODEL;       // 8M floats = 32 MB
    float* S0 = ws;          // Q -> CTX -> F2
    float* S1 = ws + T;      // K -> ATT -> H
    float* S2 = ws + 2 * T;  // V -> F1 chunks

    dim3 blk(256);
    dim3 g_proj(DMODEL / 128, NTOK / 128);        // (8, 64)

    // QKV projections
    gemm_bias_kernel<false><<<g_proj, blk, 0, stream>>>(x, Wq, bq, S0, NTOK, DMODEL, DMODEL);
    gemm_bias_kernel<false><<<g_proj, blk, 0, stream>>>(x, Wk, bk, S1, NTOK, DMODEL, DMODEL);
    gemm_bias_kernel<false><<<g_proj, blk, 0, stream>>>(x, Wv, bv, S2, NTOK, DMODEL, DMODEL);

    // attention: CTX overwrites Q in-place (per-lane read-before-write)
    attn_kernel<<<dim3(SEQ / 64, NHEADS, BATCH), dim3(64), 0, stream>>>(S0, S1, S2, S0);

    // output projection (CTX -> ATT in slot1), then LN1 in-place over ATT
    gemm_bias_kernel<false><<<g_proj, blk, 0, stream>>>(S0, Wo, bo, S1, NTOK, DMODEL, DMODEL);
    add_ln_kernel<<<dim3(NTOK), blk, 0, stream>>>(x, S1, g1, be1, S1);   // H in slot1

    // FFN in 4 row-chunks of 2048: F1 chunk (32 MB) in slot2, F2 into slot0
    const int CH = 2048;
    for (int c = 0; c < NTOK / CH; ++c) {
        const float* Hc  = S1 + (size_t)c * CH * DMODEL;
        float*       F2c = S0 + (size_t)c * CH * DMODEL;
        gemm_bias_kernel<true ><<<dim3(FFDIM / 128, CH / 128), blk, 0, stream>>>(
            Hc, W1, b1, S2, CH, FFDIM, DMODEL);
        gemm_bias_kernel<false><<<dim3(DMODEL / 128, CH / 128), blk, 0, stream>>>(
            S2, W2, b2, F2c, CH, DMODEL, FFDIM);
    }

    // final residual LN: out = LN(H + F2)
    add_ln_kernel<<<dim3(NTOK), blk, 0, stream>>>(S1, S0, g2, be2, out);
}

// Round 7
// 6661.462 us; speedup vs baseline: 1.0963x; 1.0963x over previous
//
#include <hip/hip_runtime.h>
#include <math.h>

#define DMODEL 1024
#define NHEADS 16
#define DKV    64
#define FFDIM  4096
#define SEQ    2048
#define BATCH  4
#define NTOK   (BATCH * SEQ)
#define LN_EPS 1e-5f

// Workspace budget: 3 slots x (NTOK*DMODEL) floats = 3 x 32 MB = 96 MB.
//   slot0: Q  -> CTX (attn in-place) -> F2
//   slot1: K  -> ATT (O-proj out)    -> H (LN1 in-place)
//   slot2: V  -> F1 row-chunks (2048 x 4096 = 32 MB each)

// ---------------------------------------------------------------------------
// GEMM: C[M,N] = A[M,K] @ B[K,N] + bias[N], optional ReLU.
// 128x128 tile, BK=8, 256 threads, 8x8 outputs/thread, fp32 vector FMA.
// ---------------------------------------------------------------------------
template <bool RELU>
__global__ __launch_bounds__(256) void gemm_bias_kernel(
    const float* __restrict__ A, const float* __restrict__ B,
    const float* __restrict__ bias, float* __restrict__ C,
    int M, int N, int K)
{
    __shared__ float As[8][128];   // transposed A tile: As[k][m]
    __shared__ float Bs[8][128];   // Bs[k][n]

    const int tid  = threadIdx.x;
    const int brow = blockIdx.y * 128;
    const int bcol = blockIdx.x * 128;
    const int ty   = tid >> 4;          // 0..15 -> output row group (8 rows)
    const int tx   = tid & 15;          // 0..15 -> output col group (4+4 cols)

    const int arow = tid >> 1;          // 0..127
    const int acol = (tid & 1) * 4;     // 0 or 4
    const int brw  = tid >> 5;          // 0..7
    const int bcl  = (tid & 31) * 4;    // 0..124

    float acc[8][8];
#pragma unroll
    for (int i = 0; i < 8; ++i)
#pragma unroll
        for (int j = 0; j < 8; ++j) acc[i][j] = 0.f;

    const float* Ap = A + (size_t)(brow + arow) * K + acol;
    const float* Bp = B + (size_t)brw * N + bcol + bcl;

    for (int k0 = 0; k0 < K; k0 += 8) {
        float4 a4 = *(const float4*)(Ap + k0);
        float4 b4 = *(const float4*)(Bp + (size_t)k0 * N);
        As[acol + 0][arow] = a4.x;
        As[acol + 1][arow] = a4.y;
        As[acol + 2][arow] = a4.z;
        As[acol + 3][arow] = a4.w;
        *(float4*)&Bs[brw][bcl] = b4;
        __syncthreads();
#pragma unroll
        for (int k = 0; k < 8; ++k) {
            float4 a0 = *(const float4*)&As[k][ty * 8];
            float4 a1 = *(const float4*)&As[k][ty * 8 + 4];
            float4 b0 = *(const float4*)&Bs[k][tx * 4];        // half-tile 0
            float4 b1 = *(const float4*)&Bs[k][64 + tx * 4];   // half-tile 1
            float ar[8] = {a0.x, a0.y, a0.z, a0.w, a1.x, a1.y, a1.z, a1.w};
            float br[8] = {b0.x, b0.y, b0.z, b0.w, b1.x, b1.y, b1.z, b1.w};
#pragma unroll
            for (int i = 0; i < 8; ++i)
#pragma unroll
                for (int j = 0; j < 8; ++j)
                    acc[i][j] = fmaf(ar[i], br[j], acc[i][j]);
        }
        __syncthreads();
    }

    float4 bb0 = *(const float4*)&bias[bcol + tx * 4];
    float4 bb1 = *(const float4*)&bias[bcol + 64 + tx * 4];
    float bv[8] = {bb0.x, bb0.y, bb0.z, bb0.w, bb1.x, bb1.y, bb1.z, bb1.w};
#pragma unroll
    for (int i = 0; i < 8; ++i) {
        size_t row = (size_t)(brow + ty * 8 + i);
        float o[8];
#pragma unroll
        for (int j = 0; j < 8; ++j) {
            o[j] = acc[i][j] + bv[j];
            if (RELU) o[j] = fmaxf(o[j], 0.f);
        }
        *(float4*)&C[row * N + bcol + tx * 4]      = make_float4(o[0], o[1], o[2], o[3]);
        *(float4*)&C[row * N + bcol + 64 + tx * 4] = make_float4(o[4], o[5], o[6], o[7]);
    }
}

// ---------------------------------------------------------------------------
// Flash-style attention, fp32, NO LDS. grid = (SEQ/64, NHEADS, BATCH),
// 64 threads (1 wave). Each lane owns one q-row (q + acc in registers).
// K/V row addresses are wave-uniform (loop-derived) -> compiler scalarizes
// the loads into s_load on the scalar pipe (K/V per head = 1 MB, L2-hot),
// used as the one legal SGPR operand of v_fma. No barriers, no LDS pipe.
// 2-key batching per iteration for load/VALU ILP and fewer rescales.
// CTX may alias Q (in-place): q fully read into regs before writeout.
// ---------------------------------------------------------------------------
__global__ __launch_bounds__(64) void attn_kernel(
    const float* Q, const float* __restrict__ K,
    const float* __restrict__ V, float* CTX)
{
    const int qt   = blockIdx.x;   // 0..31
    const int h    = blockIdx.y;   // 0..15
    const int b    = blockIdx.z;   // 0..3
    const int lane = threadIdx.x;  // 0..63

    const size_t headbase = (size_t)(b * SEQ) * DMODEL + (size_t)h * DKV;
    const float* qrow = Q + headbase + (size_t)(qt * 64 + lane) * DMODEL;

    float q[64];
#pragma unroll
    for (int d = 0; d < 64; d += 4) {
        float4 t = *(const float4*)&qrow[d];
        q[d]     = t.x * 0.125f;   // fold 1/sqrt(dk)=1/8 into q
        q[d + 1] = t.y * 0.125f;
        q[d + 2] = t.z * 0.125f;
        q[d + 3] = t.w * 0.125f;
    }
    float acc[64];
#pragma unroll
    for (int d = 0; d < 64; ++d) acc[d] = 0.f;
    float m = -INFINITY, l = 0.f;

    const float* Kh = K + headbase;
    const float* Vh = V + headbase;

    for (int kk = 0; kk < SEQ; kk += 2) {
        const float* Ka = Kh + (size_t)kk * DMODEL;        // wave-uniform
        const float* Kb = Ka + DMODEL;                     // wave-uniform
        float a0 = 0.f, a1 = 0.f, a2 = 0.f, a3 = 0.f;
        float c0 = 0.f, c1 = 0.f, c2 = 0.f, c3 = 0.f;
#pragma unroll
        for (int d = 0; d < 64; d += 4) {
            a0 = fmaf(q[d],     Ka[d],     a0);
            a1 = fmaf(q[d + 1], Ka[d + 1], a1);
            a2 = fmaf(q[d + 2], Ka[d + 2], a2);
            a3 = fmaf(q[d + 3], Ka[d + 3], a3);
            c0 = fmaf(q[d],     Kb[d],     c0);
            c1 = fmaf(q[d + 1], Kb[d + 1], c1);
            c2 = fmaf(q[d + 2], Kb[d + 2], c2);
            c3 = fmaf(q[d + 3], Kb[d + 3], c3);
        }
        float sa = (a0 + a1) + (a2 + a3);
        float sb = (c0 + c1) + (c2 + c3);

        float mn = fmaxf(m, fmaxf(sa, sb));
        if (mn > m) {                    // rare after warm-up
            float c = __expf(m - mn);    // exp(-inf)=0 on first tile: correct
            l *= c;
#pragma unroll
            for (int d = 0; d < 64; ++d) acc[d] *= c;
            m = mn;
        }
        float pa = __expf(sa - m);
        float pb = __expf(sb - m);
        l += pa + pb;

        const float* Va = Vh + (size_t)kk * DMODEL;        // wave-uniform
        const float* Vb = Va + DMODEL;                     // wave-uniform
#pragma unroll
        for (int d = 0; d < 64; ++d)
            acc[d] = fmaf(pb, Vb[d], fmaf(pa, Va[d], acc[d]));
    }

    const float invl = 1.0f / l;
    float* orow = CTX + headbase + (size_t)(qt * 64 + lane) * DMODEL;
#pragma unroll
    for (int d = 0; d < 64; d += 4) {
        *(float4*)&orow[d] = make_float4(acc[d] * invl, acc[d + 1] * invl,
                                         acc[d + 2] * invl, acc[d + 3] * invl);
    }
}

// ---------------------------------------------------------------------------
// OUT[row] = LayerNorm(X[row] + Y[row]) * g + be.  One block per row.
// OUT may alias Y (in-place): per-thread loads precede the store.
// ---------------------------------------------------------------------------
__global__ __launch_bounds__(256) void add_ln_kernel(
    const float* X, const float* Y,
    const float* __restrict__ g, const float* __restrict__ be,
    float* OUT)
{
    const int row = blockIdx.x;
    const int tid = threadIdx.x;
    const size_t base = (size_t)row * DMODEL + (size_t)tid * 4;

    float4 x4 = *(const float4*)&X[base];
    float4 y4 = *(const float4*)&Y[base];
    float4 s4 = make_float4(x4.x + y4.x, x4.y + y4.y, x4.z + y4.z, x4.w + y4.w);
    float sum = s4.x + s4.y + s4.z + s4.w;
    float sq  = s4.x * s4.x + s4.y * s4.y + s4.z * s4.z + s4.w * s4.w;
#pragma unroll
    for (int off = 32; off > 0; off >>= 1) {
        sum += __shfl_down(sum, off);
        sq  += __shfl_down(sq, off);
    }
    __shared__ float red[8];
    const int wid = tid >> 6, ln = tid & 63;
    if (ln == 0) { red[wid] = sum; red[4 + wid] = sq; }
    __syncthreads();
    if (tid == 0) {
        float s  = red[0] + red[1] + red[2] + red[3];
        float qq = red[4] + red[5] + red[6] + red[7];
        float mu  = s * (1.0f / DMODEL);
        float var = qq * (1.0f / DMODEL) - mu * mu;
        red[0] = mu;
        red[1] = rsqrtf(var + LN_EPS);
    }
    __syncthreads();
    const float mu = red[0], rs = red[1];
    float4 g4 = *(const float4*)&g[(size_t)tid * 4];
    float4 b4 = *(const float4*)&be[(size_t)tid * 4];
    float4 o;
    o.x = (s4.x - mu) * rs * g4.x + b4.x;
    o.y = (s4.y - mu) * rs * g4.y + b4.y;
    o.z = (s4.z - mu) * rs * g4.z + b4.z;
    o.w = (s4.w - mu) * rs * g4.w + b4.w;
    *(float4*)&OUT[base] = o;
}

// ---------------------------------------------------------------------------
extern "C" void kernel_launch(void* const* d_in, const int* in_sizes, int n_in,
                              void* d_out, int out_size, void* d_ws, size_t ws_size,
                              hipStream_t stream)
{
    const float* x   = (const float*)d_in[0];
    const float* Wq  = (const float*)d_in[1];
    const float* bq  = (const float*)d_in[2];
    const float* Wk  = (const float*)d_in[3];
    const float* bk  = (const float*)d_in[4];
    const float* Wv  = (const float*)d_in[5];
    const float* bv  = (const float*)d_in[6];
    const float* Wo  = (const float*)d_in[7];
    const float* bo  = (const float*)d_in[8];
    const float* W1  = (const float*)d_in[9];
    const float* b1  = (const float*)d_in[10];
    const float* W2  = (const float*)d_in[11];
    const float* b2  = (const float*)d_in[12];
    const float* g1  = (const float*)d_in[13];
    const float* be1 = (const float*)d_in[14];
    const float* g2  = (const float*)d_in[15];
    const float* be2 = (const float*)d_in[16];
    float* out = (float*)d_out;

    float* ws = (float*)d_ws;
    const size_t T = (size_t)NTOK * DMODEL;       // 8M floats = 32 MB
    float* S0 = ws;          // Q -> CTX -> F2
    float* S1 = ws + T;      // K -> ATT -> H
    float* S2 = ws + 2 * T;  // V -> F1 chunks

    dim3 blk(256);
    dim3 g_proj(DMODEL / 128, NTOK / 128);        // (8, 64)

    // QKV projections
    gemm_bias_kernel<false><<<g_proj, blk, 0, stream>>>(x, Wq, bq, S0, NTOK, DMODEL, DMODEL);
    gemm_bias_kernel<false><<<g_proj, blk, 0, stream>>>(x, Wk, bk, S1, NTOK, DMODEL, DMODEL);
    gemm_bias_kernel<false><<<g_proj, blk, 0, stream>>>(x, Wv, bv, S2, NTOK, DMODEL, DMODEL);

    // attention: CTX overwrites Q in-place (per-lane read-before-write)
    attn_kernel<<<dim3(SEQ / 64, NHEADS, BATCH), dim3(64), 0, stream>>>(S0, S1, S2, S0);

    // output projection (CTX -> ATT in slot1), then LN1 in-place over ATT
    gemm_bias_kernel<false><<<g_proj, blk, 0, stream>>>(S0, Wo, bo, S1, NTOK, DMODEL, DMODEL);
    add_ln_kernel<<<dim3(NTOK), blk, 0, stream>>>(x, S1, g1, be1, S1);   // H in slot1

    // FFN in 4 row-chunks of 2048: F1 chunk (32 MB) in slot2, F2 into slot0
    const int CH = 2048;
    for (int c = 0; c < NTOK / CH; ++c) {
        const float* Hc  = S1 + (size_t)c * CH * DMODEL;
        float*       F2c = S0 + (size_t)c * CH * DMODEL;
        gemm_bias_kernel<true ><<<dim3(FFDIM / 128, CH / 128), blk, 0, stream>>>(
            Hc, W1, b1, S2, CH, FFDIM, DMODEL);
        gemm_bias_kernel<false><<<dim3(DMODEL / 128, CH / 128), blk, 0, stream>>>(
            S2, W2, b2, F2c, CH, DMODEL, FFDIM);
    }

    // final residual LN: out = LN(H + F2)
    add_ln_kernel<<<dim3(NTOK), blk, 0, stream>>>(S1, S0, g2, be2, out);
}

// Round 8
// 3534.631 us; speedup vs baseline: 2.0661x; 1.8846x over previous
//
#include <hip/hip_runtime.h>
#include <math.h>

#define DMODEL 1024
#define NHEADS 16
#define DKV    64
#define FFDIM  4096
#define SEQ    2048
#define BATCH  4
#define NTOK   (BATCH * SEQ)
#define LN_EPS 1e-5f

typedef unsigned short u16;
typedef __attribute__((ext_vector_type(8))) short   short8;   // 8 bf16 = 4 VGPR
typedef __attribute__((ext_vector_type(4))) float   f32x4;

// d_ws: 3 x 32MB slots (proven-safe 96MB):
//   S0: Q fp32 -> ctx fp32 (attn in-place) -> F2 fp32 chunks
//   S1: K fp32 -> ATT fp32 (O-proj) -> H fp32 (LN1 in-place)
//   S2: V fp32 -> F1 fp32 chunks (2048 x 4096)
// d_out doubles as scratch for transposed bf16 weights (24MB); the final
// add_ln overwrites every element of d_out at the end.

// ---------------------------------------------------------------------------
// Weight transpose + fp32->bf16(RNE): W[K,N] -> WT[N][K] (k-contiguous).
// ---------------------------------------------------------------------------
__global__ __launch_bounds__(256) void transpose_cvt_kernel(
    const float* __restrict__ W, u16* __restrict__ WT, int K, int N)
{
    __shared__ u16 T[64][72];            // pad 72: byte stride 144 (16B-mult)
    const int n0 = blockIdx.x * 64;
    const int k0 = blockIdx.y * 64;
    const int t  = threadIdx.x;

    const int r  = t >> 4;               // 0..15
    const int c4 = (t & 15) * 4;         // 0..60
#pragma unroll
    for (int rr = 0; rr < 64; rr += 16) {
        float4 w = *(const float4*)&W[(size_t)(k0 + r + rr) * N + n0 + c4];
        float wf[4] = {w.x, w.y, w.z, w.w};
#pragma unroll
        for (int i = 0; i < 4; ++i) {
            unsigned u = __float_as_uint(wf[i]);
            u16 h = (u16)((u + 0x7FFFu + ((u >> 16) & 1u)) >> 16);   // RNE
            T[c4 + i][r + rr] = h;
        }
    }
    __syncthreads();

    const int nr = t >> 2;               // 0..63
    const int q  = t & 3;                // 0..3 -> 16 k each
    short8 v0 = *(const short8*)&T[nr][q * 16];
    short8 v1 = *(const short8*)&T[nr][q * 16 + 8];
    u16* dst = WT + (size_t)(n0 + nr) * K + k0 + q * 16;
    *(short8*)dst       = v0;
    *(short8*)(dst + 8) = v1;
}

// ---------------------------------------------------------------------------
// Split-bf16 MFMA GEMM: C[M,N] = A[M,K](fp32) @ B[K,N] + bias, opt ReLU.
// B supplied pre-transposed bf16: BT[N][K]. A split to hi/lo bf16 in LDS
// during staging; 2 mfma passes (hi*B + lo*B) accumulate in fp32.
// 128x128 tile, BK=32, 256 thr = 4 waves (2x2), wave tile 64x64 = 4x4 frags
// of mfma_f32_16x16x32_bf16. LDS rows padded to 40 elems -> frag ds_read_b128
// lane banks <=2-way (free).
// ---------------------------------------------------------------------------
template <bool RELU>
__global__ __launch_bounds__(256) void gemm_mfma_kernel(
    const float* __restrict__ A, const u16* __restrict__ BT,
    const float* __restrict__ bias, float* __restrict__ C,
    int M, int N, int K)
{
    __shared__ u16 Ah[128][40];
    __shared__ u16 Al[128][40];
    __shared__ u16 Bs[128][40];

    const int tid  = threadIdx.x;
    const int lane = tid & 63;
    const int wave = tid >> 6;
    const int wr   = wave >> 1;          // 0..1
    const int wc   = wave & 1;           // 0..1
    const int brow = blockIdx.y * 128;
    const int bcol = blockIdx.x * 128;

    // staging assignment: each thread covers one row-half (16 k) of A and B
    const int srow = tid >> 1;           // 0..127
    const int sk   = (tid & 1) * 16;     // 0 or 16

    const float* ap = A  + (size_t)(brow + srow) * K + sk;
    const u16*   bp = BT + (size_t)(bcol + srow) * K + sk;

    const int lrow = lane & 15;
    const int lk   = (lane >> 4) * 8;

    f32x4 acc[4][4];
#pragma unroll
    for (int m = 0; m < 4; ++m)
#pragma unroll
        for (int n = 0; n < 4; ++n) acc[m][n] = (f32x4){0.f, 0.f, 0.f, 0.f};

    for (int k0 = 0; k0 < K; k0 += 32) {
        // ---- stage A (fp32 -> hi/lo bf16) and B (bf16 copy) ----
        float4 f0 = *(const float4*)(ap + k0);
        float4 f1 = *(const float4*)(ap + k0 + 4);
        float4 f2 = *(const float4*)(ap + k0 + 8);
        float4 f3 = *(const float4*)(ap + k0 + 12);
        float fa[16] = {f0.x, f0.y, f0.z, f0.w, f1.x, f1.y, f1.z, f1.w,
                        f2.x, f2.y, f2.z, f2.w, f3.x, f3.y, f3.z, f3.w};
        short8 hi0, hi1, lo0, lo1;
#pragma unroll
        for (int i = 0; i < 8; ++i) {
            unsigned u = __float_as_uint(fa[i]);
            hi0[i] = (short)(u >> 16);                       // truncate hi
            float hf = __uint_as_float(u & 0xFFFF0000u);
            lo0[i] = (short)(__float_as_uint(fa[i] - hf) >> 16);
        }
#pragma unroll
        for (int i = 0; i < 8; ++i) {
            unsigned u = __float_as_uint(fa[8 + i]);
            hi1[i] = (short)(u >> 16);
            float hf = __uint_as_float(u & 0xFFFF0000u);
            lo1[i] = (short)(__float_as_uint(fa[8 + i] - hf) >> 16);
        }
        short8 b0 = *(const short8*)(bp + k0);
        short8 b1 = *(const short8*)(bp + k0 + 8);

        *(short8*)&Ah[srow][sk]     = hi0;
        *(short8*)&Ah[srow][sk + 8] = hi1;
        *(short8*)&Al[srow][sk]     = lo0;
        *(short8*)&Al[srow][sk + 8] = lo1;
        *(short8*)&Bs[srow][sk]     = b0;
        *(short8*)&Bs[srow][sk + 8] = b1;
        __syncthreads();

        // ---- fragments + 2-pass mfma ----
        short8 afh[4], afl[4], bf[4];
#pragma unroll
        for (int m = 0; m < 4; ++m) {
            afh[m] = *(const short8*)&Ah[wr * 64 + m * 16 + lrow][lk];
            afl[m] = *(const short8*)&Al[wr * 64 + m * 16 + lrow][lk];
        }
#pragma unroll
        for (int n = 0; n < 4; ++n)
            bf[n] = *(const short8*)&Bs[wc * 64 + n * 16 + lrow][lk];
#pragma unroll
        for (int m = 0; m < 4; ++m)
#pragma unroll
            for (int n = 0; n < 4; ++n) {
                acc[m][n] = __builtin_amdgcn_mfma_f32_16x16x32_bf16(
                    afh[m], bf[n], acc[m][n], 0, 0, 0);
                acc[m][n] = __builtin_amdgcn_mfma_f32_16x16x32_bf16(
                    afl[m], bf[n], acc[m][n], 0, 0, 0);
            }
        __syncthreads();
    }

    // ---- epilogue: bias (+ReLU), fp32 store ----
    float bv[4];
#pragma unroll
    for (int n = 0; n < 4; ++n)
        bv[n] = bias[bcol + wc * 64 + n * 16 + (lane & 15)];
#pragma unroll
    for (int m = 0; m < 4; ++m)
#pragma unroll
        for (int n = 0; n < 4; ++n) {
            const int col = bcol + wc * 64 + n * 16 + (lane & 15);
#pragma unroll
            for (int j = 0; j < 4; ++j) {
                const int row = brow + wr * 64 + m * 16 + (lane >> 4) * 4 + j;
                float v = acc[m][n][j] + bv[n];
                if (RELU) v = fmaxf(v, 0.f);
                C[(size_t)row * N + col] = v;
            }
        }
}

// ---------------------------------------------------------------------------
// Flash-style attention, fp32, no LDS (unchanged from R7; 2380us, latency-
// bound — MFMA rewrite is next round's target).
// ---------------------------------------------------------------------------
__global__ __launch_bounds__(64) void attn_kernel(
    const float* Q, const float* __restrict__ K,
    const float* __restrict__ V, float* CTX)
{
    const int qt   = blockIdx.x;
    const int h    = blockIdx.y;
    const int b    = blockIdx.z;
    const int lane = threadIdx.x;

    const size_t headbase = (size_t)(b * SEQ) * DMODEL + (size_t)h * DKV;
    const float* qrow = Q + headbase + (size_t)(qt * 64 + lane) * DMODEL;

    float q[64];
#pragma unroll
    for (int d = 0; d < 64; d += 4) {
        float4 t = *(const float4*)&qrow[d];
        q[d]     = t.x * 0.125f;
        q[d + 1] = t.y * 0.125f;
        q[d + 2] = t.z * 0.125f;
        q[d + 3] = t.w * 0.125f;
    }
    float acc[64];
#pragma unroll
    for (int d = 0; d < 64; ++d) acc[d] = 0.f;
    float m = -INFINITY, l = 0.f;

    const float* Kh = K + headbase;
    const float* Vh = V + headbase;

    for (int kk = 0; kk < SEQ; kk += 2) {
        const float* Ka = Kh + (size_t)kk * DMODEL;
        const float* Kb = Ka + DMODEL;
        float a0 = 0.f, a1 = 0.f, a2 = 0.f, a3 = 0.f;
        float c0 = 0.f, c1 = 0.f, c2 = 0.f, c3 = 0.f;
#pragma unroll
        for (int d = 0; d < 64; d += 4) {
            a0 = fmaf(q[d],     Ka[d],     a0);
            a1 = fmaf(q[d + 1], Ka[d + 1], a1);
            a2 = fmaf(q[d + 2], Ka[d + 2], a2);
            a3 = fmaf(q[d + 3], Ka[d + 3], a3);
            c0 = fmaf(q[d],     Kb[d],     c0);
            c1 = fmaf(q[d + 1], Kb[d + 1], c1);
            c2 = fmaf(q[d + 2], Kb[d + 2], c2);
            c3 = fmaf(q[d + 3], Kb[d + 3], c3);
        }
        float sa = (a0 + a1) + (a2 + a3);
        float sb = (c0 + c1) + (c2 + c3);

        float mn = fmaxf(m, fmaxf(sa, sb));
        if (mn > m) {
            float c = __expf(m - mn);
            l *= c;
#pragma unroll
            for (int d = 0; d < 64; ++d) acc[d] *= c;
            m = mn;
        }
        float pa = __expf(sa - m);
        float pb = __expf(sb - m);
        l += pa + pb;

        const float* Va = Vh + (size_t)kk * DMODEL;
        const float* Vb = Va + DMODEL;
#pragma unroll
        for (int d = 0; d < 64; ++d)
            acc[d] = fmaf(pb, Vb[d], fmaf(pa, Va[d], acc[d]));
    }

    const float invl = 1.0f / l;
    float* orow = CTX + headbase + (size_t)(qt * 64 + lane) * DMODEL;
#pragma unroll
    for (int d = 0; d < 64; d += 4) {
        *(float4*)&orow[d] = make_float4(acc[d] * invl, acc[d + 1] * invl,
                                         acc[d + 2] * invl, acc[d + 3] * invl);
    }
}

// ---------------------------------------------------------------------------
// OUT[row] = LayerNorm(X[row] + Y[row]) * g + be.  One block per row.
// OUT may alias Y (in-place): per-thread loads precede the store.
// ---------------------------------------------------------------------------
__global__ __launch_bounds__(256) void add_ln_kernel(
    const float* X, const float* Y,
    const float* __restrict__ g, const float* __restrict__ be,
    float* OUT)
{
    const int row = blockIdx.x;
    const int tid = threadIdx.x;
    const size_t base = (size_t)row * DMODEL + (size_t)tid * 4;

    float4 x4 = *(const float4*)&X[base];
    float4 y4 = *(const float4*)&Y[base];
    float4 s4 = make_float4(x4.x + y4.x, x4.y + y4.y, x4.z + y4.z, x4.w + y4.w);
    float sum = s4.x + s4.y + s4.z + s4.w;
    float sq  = s4.x * s4.x + s4.y * s4.y + s4.z * s4.z + s4.w * s4.w;
#pragma unroll
    for (int off = 32; off > 0; off >>= 1) {
        sum += __shfl_down(sum, off);
        sq  += __shfl_down(sq, off);
    }
    __shared__ float red[8];
    const int wid = tid >> 6, ln = tid & 63;
    if (ln == 0) { red[wid] = sum; red[4 + wid] = sq; }
    __syncthreads();
    if (tid == 0) {
        float s  = red[0] + red[1] + red[2] + red[3];
        float qq = red[4] + red[5] + red[6] + red[7];
        float mu  = s * (1.0f / DMODEL);
        float var = qq * (1.0f / DMODEL) - mu * mu;
        red[0] = mu;
        red[1] = rsqrtf(var + LN_EPS);
    }
    __syncthreads();
    const float mu = red[0], rs = red[1];
    float4 g4 = *(const float4*)&g[(size_t)tid * 4];
    float4 b4 = *(const float4*)&be[(size_t)tid * 4];
    float4 o;
    o.x = (s4.x - mu) * rs * g4.x + b4.x;
    o.y = (s4.y - mu) * rs * g4.y + b4.y;
    o.z = (s4.z - mu) * rs * g4.z + b4.z;
    o.w = (s4.w - mu) * rs * g4.w + b4.w;
    *(float4*)&OUT[base] = o;
}

// ---------------------------------------------------------------------------
extern "C" void kernel_launch(void* const* d_in, const int* in_sizes, int n_in,
                              void* d_out, int out_size, void* d_ws, size_t ws_size,
                              hipStream_t stream)
{
    const float* x   = (const float*)d_in[0];
    const float* Wq  = (const float*)d_in[1];
    const float* bq  = (const float*)d_in[2];
    const float* Wk  = (const float*)d_in[3];
    const float* bk  = (const float*)d_in[4];
    const float* Wv  = (const float*)d_in[5];
    const float* bv  = (const float*)d_in[6];
    const float* Wo  = (const float*)d_in[7];
    const float* bo  = (const float*)d_in[8];
    const float* W1  = (const float*)d_in[9];
    const float* b1  = (const float*)d_in[10];
    const float* W2  = (const float*)d_in[11];
    const float* b2  = (const float*)d_in[12];
    const float* g1  = (const float*)d_in[13];
    const float* be1 = (const float*)d_in[14];
    const float* g2  = (const float*)d_in[15];
    const float* be2 = (const float*)d_in[16];
    float* out = (float*)d_out;

    float* ws = (float*)d_ws;
    const size_t T = (size_t)NTOK * DMODEL;       // 8M floats = 32 MB
    float* S0 = ws;          // Q -> ctx -> F2
    float* S1 = ws + T;      // K -> ATT -> H
    float* S2 = ws + 2 * T;  // V -> F1 chunks

    // transposed bf16 weights live in d_out scratch (final LN overwrites)
    u16* wt  = (u16*)d_out;
    u16* WqT = wt;                         // [1024][1024]
    u16* WkT = wt + (size_t)1  * 1024 * 1024;
    u16* WvT = wt + (size_t)2  * 1024 * 1024;
    u16* WoT = wt + (size_t)3  * 1024 * 1024;
    u16* W1T = wt + (size_t)4  * 1024 * 1024;   // [4096][1024]
    u16* W2T = wt + (size_t)8  * 1024 * 1024;   // [1024][4096]

    dim3 blk(256);

    // 1) weight transpose+convert (into d_out scratch)
    transpose_cvt_kernel<<<dim3(16, 16), blk, 0, stream>>>(Wq, WqT, DMODEL, DMODEL);
    transpose_cvt_kernel<<<dim3(16, 16), blk, 0, stream>>>(Wk, WkT, DMODEL, DMODEL);
    transpose_cvt_kernel<<<dim3(16, 16), blk, 0, stream>>>(Wv, WvT, DMODEL, DMODEL);
    transpose_cvt_kernel<<<dim3(16, 16), blk, 0, stream>>>(Wo, WoT, DMODEL, DMODEL);
    transpose_cvt_kernel<<<dim3(64, 16), blk, 0, stream>>>(W1, W1T, DMODEL, FFDIM);
    transpose_cvt_kernel<<<dim3(16, 64), blk, 0, stream>>>(W2, W2T, FFDIM, DMODEL);

    dim3 g_proj(DMODEL / 128, NTOK / 128);        // (8, 64)

    // 2) QKV projections (split-bf16 MFMA)
    gemm_mfma_kernel<false><<<g_proj, blk, 0, stream>>>(x, WqT, bq, S0, NTOK, DMODEL, DMODEL);
    gemm_mfma_kernel<false><<<g_proj, blk, 0, stream>>>(x, WkT, bk, S1, NTOK, DMODEL, DMODEL);
    gemm_mfma_kernel<false><<<g_proj, blk, 0, stream>>>(x, WvT, bv, S2, NTOK, DMODEL, DMODEL);

    // 3) attention (ctx over Q in-place)
    attn_kernel<<<dim3(SEQ / 64, NHEADS, BATCH), dim3(64), 0, stream>>>(S0, S1, S2, S0);

    // 4) O-projection + LN1 (H in-place in S1)
    gemm_mfma_kernel<false><<<g_proj, blk, 0, stream>>>(S0, WoT, bo, S1, NTOK, DMODEL, DMODEL);
    add_ln_kernel<<<dim3(NTOK), blk, 0, stream>>>(x, S1, g1, be1, S1);

    // 5) FFN in 4 row-chunks of 2048 (F1 fp32 chunk in S2, F2 into S0)
    const int CH = 2048;
    for (int c = 0; c < NTOK / CH; ++c) {
        const float* Hc  = S1 + (size_t)c * CH * DMODEL;
        float*       F2c = S0 + (size_t)c * CH * DMODEL;
        gemm_mfma_kernel<true ><<<dim3(FFDIM / 128, CH / 128), blk, 0, stream>>>(
            Hc, W1T, b1, S2, CH, FFDIM, DMODEL);
        gemm_mfma_kernel<false><<<dim3(DMODEL / 128, CH / 128), blk, 0, stream>>>(
            S2, W2T, b2, F2c, CH, DMODEL, FFDIM);
    }

    // 6) final residual LN (overwrites the WT scratch in d_out)
    add_ln_kernel<<<dim3(NTOK), blk, 0, stream>>>(S1, S0, g2, be2, out);
}